// Round 3
// baseline (142.829 us; speedup 1.0000x reference)
//
#include <hip/hip_runtime.h>
#include <hip/hip_bf16.h>

typedef unsigned short u16;
typedef __attribute__((ext_vector_type(8))) short short8;
typedef __attribute__((ext_vector_type(4))) float f32x4;

#define B_ 32
#define L_ 1024
#define D_ 1024
#define E_ 100
#define E1_ 101
#define M2_ (B_ * E1_)     // 3232 entity rows (incl. none-entity)
#define M2P_ 3264          // padded to 51*64 for MFMA tiles
#define QBLK_ 32
#define NBLK3_ 7           // tiles that can contain valid rows (Q_MAX=200 < 7*32)

#define MFMA16(a, b, c) __builtin_amdgcn_mfma_f32_16x16x32_bf16((a), (b), (c), 0, 0, 0)

__device__ __forceinline__ void split2(float x, u16& h, u16& l) {
    __hip_bfloat16 bh = __float2bfloat16(x);          // RN
    float r = x - __bfloat162float(bh);
    __hip_bfloat16 bl = __float2bfloat16(r);
    h = __builtin_bit_cast(u16, bh);
    l = __builtin_bit_cast(u16, bl);
}

// ---------------- K1: segment-sum -> enc hi/lo bf16 split; fused last column
// ep_last[be] = dot(enc_row, W[1024,:]) + bias[1024]
__global__ __launch_bounds__(256) void k_encode(const float* __restrict__ q_enc,
                                                const float* __restrict__ none_ent,
                                                const float* __restrict__ W,
                                                const float* __restrict__ bias,
                                                const int* __restrict__ ranges,
                                                u16* __restrict__ enc_hi, u16* __restrict__ enc_lo,
                                                float* __restrict__ ep_last) {
    __shared__ float red4[4];
    int be = blockIdx.x;
    int b = be / E1_, e = be - b * E1_;
    int t = threadIdx.x, c = t * 4;
    float4 acc;
    if (e == E_) {
        acc = *(const float4*)&none_ent[c];
    } else {
        acc = make_float4(0.f, 0.f, 0.f, 0.f);
        int r0 = ranges[(b * E_ + e) * 2 + 0];
        int r1 = ranges[(b * E_ + e) * 2 + 1];
        for (int l = r0 + 1; l < r1; ++l) {
            float4 v = *(const float4*)&q_enc[((size_t)b * L_ + l) * D_ + c];
            acc.x += v.x; acc.y += v.y; acc.z += v.z; acc.w += v.w;
        }
    }
    union { u16 u[4]; float2 f; } ph, pl;
    split2(acc.x, ph.u[0], pl.u[0]); split2(acc.y, ph.u[1], pl.u[1]);
    split2(acc.z, ph.u[2], pl.u[2]); split2(acc.w, ph.u[3], pl.u[3]);
    *(float2*)&enc_hi[(size_t)be * 1024 + c] = ph.f;
    *(float2*)&enc_lo[(size_t)be * 1024 + c] = pl.f;
    // fused last column (hint-weight row of W)
    const float* w1k = W + (size_t)1024 * 1024;
    float4 wv = *(const float4*)&w1k[c];
    float s = acc.x * wv.x + acc.y * wv.y + acc.z * wv.z + acc.w * wv.w;
    #pragma unroll
    for (int off = 32; off; off >>= 1) s += __shfl_down(s, off);
    if ((t & 63) == 0) red4[t >> 6] = s;
    __syncthreads();
    if (t == 0) ep_last[be] = red4[0] + red4[1] + red4[2] + red4[3] + bias[1024];
}

// ---------------- K2: W rows 0..1023 -> bf16 hi/lo
__global__ __launch_bounds__(256) void k_wsplit(const float* __restrict__ W,
                                                u16* __restrict__ w_hi, u16* __restrict__ w_lo) {
    int r = blockIdx.x, c = threadIdx.x * 4;
    float4 v = *(const float4*)&W[(size_t)r * 1024 + c];
    union { u16 u[4]; float2 f; } ph, pl;
    split2(v.x, ph.u[0], pl.u[0]); split2(v.y, ph.u[1], pl.u[1]);
    split2(v.z, ph.u[2], pl.u[2]); split2(v.w, ph.u[3], pl.u[3]);
    *(float2*)&w_hi[(size_t)r * 1024 + c] = ph.f;
    *(float2*)&w_lo[(size_t)r * 1024 + c] = pl.f;
}

// ---------------- K3: ep[m][n] = enc[m][:] . W[n][:] + bias[n], 3-term bf16 MFMA
// 64x64 tile, BK=64, 4 waves (2x2), wave = 32x32 = 2x2 frags of 16x16x32.
__global__ __launch_bounds__(256) void k_entproj(const u16* __restrict__ A_hi, const u16* __restrict__ A_lo,
                                                 const u16* __restrict__ B_hi, const u16* __restrict__ B_lo,
                                                 const float* __restrict__ bias,
                                                 u16* __restrict__ ep_hi, u16* __restrict__ ep_lo) {
    __shared__ __attribute__((aligned(16))) u16 Ah[64 * 64], Al[64 * 64], Bh[64 * 64], Bl[64 * 64];
    int tid = threadIdx.x;
    int m0 = blockIdx.y * 64, n0 = blockIdx.x * 64;
    int w = tid >> 6, lane = tid & 63, lr = lane & 15, lg = lane >> 4;
    int wr = w >> 1, wc = w & 1;
    f32x4 zero = {0.f, 0.f, 0.f, 0.f};
    f32x4 acc[2][2] = {{zero, zero}, {zero, zero}};
    for (int k0 = 0; k0 < 1024; k0 += 64) {
        #pragma unroll
        for (int p = 0; p < 2; ++p) {
            int i = p * 256 + tid, r = i >> 3, s = i & 7;
            int dst = r * 64 + ((s ^ (r & 7)) << 3);
            size_t ga = (size_t)(m0 + r) * 1024 + k0 + s * 8;
            size_t gb = (size_t)(n0 + r) * 1024 + k0 + s * 8;
            *(float4*)&Ah[dst] = *(const float4*)&A_hi[ga];
            *(float4*)&Al[dst] = *(const float4*)&A_lo[ga];
            *(float4*)&Bh[dst] = *(const float4*)&B_hi[gb];
            *(float4*)&Bl[dst] = *(const float4*)&B_lo[gb];
        }
        __syncthreads();
        #pragma unroll
        for (int ks = 0; ks < 64; ks += 32) {
            int sk = (ks >> 3) + lg;
            short8 ah[2], al[2], bh[2], bl[2];
            #pragma unroll
            for (int mf = 0; mf < 2; ++mf) {
                int r = wr * 32 + mf * 16 + lr;
                int ad = r * 64 + ((sk ^ (r & 7)) << 3);
                ah[mf] = __builtin_bit_cast(short8, *(const float4*)&Ah[ad]);
                al[mf] = __builtin_bit_cast(short8, *(const float4*)&Al[ad]);
            }
            #pragma unroll
            for (int nf = 0; nf < 2; ++nf) {
                int r = wc * 32 + nf * 16 + lr;
                int ad = r * 64 + ((sk ^ (r & 7)) << 3);
                bh[nf] = __builtin_bit_cast(short8, *(const float4*)&Bh[ad]);
                bl[nf] = __builtin_bit_cast(short8, *(const float4*)&Bl[ad]);
            }
            #pragma unroll
            for (int mf = 0; mf < 2; ++mf)
                #pragma unroll
                for (int nf = 0; nf < 2; ++nf) {
                    acc[mf][nf] = MFMA16(ah[mf], bh[nf], acc[mf][nf]);
                    acc[mf][nf] = MFMA16(ah[mf], bl[nf], acc[mf][nf]);
                    acc[mf][nf] = MFMA16(al[mf], bh[nf], acc[mf][nf]);
                }
        }
        __syncthreads();
    }
    #pragma unroll
    for (int mf = 0; mf < 2; ++mf)
        #pragma unroll
        for (int nf = 0; nf < 2; ++nf)
            #pragma unroll
            for (int reg = 0; reg < 4; ++reg) {
                int m = m0 + wr * 32 + mf * 16 + lg * 4 + reg;
                if (m < M2_) {
                    int n = n0 + wc * 32 + nf * 16 + lr;
                    float v = acc[mf][nf][reg] + bias[n];
                    u16 h, l;
                    split2(v, h, l);
                    ep_hi[(size_t)m * 1024 + n] = h;
                    ep_lo[(size_t)m * 1024 + n] = l;
                }
            }
}

// ---------------- K4: scores (MFMA) + fused softmax + co_att (incl. zeroing masked rows)
// grid = (L/32, B). Tiles fully past qlen just zero their co_att region.
__global__ __launch_bounds__(256) void k_scores(const float* __restrict__ q_enc,
                                                const float* __restrict__ hint,
                                                const u16* __restrict__ ep_hi, const u16* __restrict__ ep_lo,
                                                const float* __restrict__ ep_last,
                                                const int* __restrict__ qlen,
                                                float* __restrict__ co_att,
                                                float* __restrict__ partial) {
    __shared__ __attribute__((aligned(16))) u16 Ah[32 * 64], Al[32 * 64], Bh[112 * 64], Bl[112 * 64];
    __shared__ float Ss[32 * 113];
    __shared__ float red[QBLK_][8];
    int b = blockIdx.y, mt = blockIdx.x, l0 = mt * QBLK_;
    int tid = threadIdx.x;
    int qn = qlen[b];
    if (l0 >= qn) {
        // zero this tile's co_att rows (32*101 floats = 808 float4, 16B-aligned)
        float* base = &co_att[((size_t)b * L_ + l0) * E1_];
        float4 z = make_float4(0.f, 0.f, 0.f, 0.f);
        for (int i = tid; i < QBLK_ * E1_ / 4; i += 256)
            *(float4*)&base[i * 4] = z;
        if (mt < NBLK3_)
            for (int e = tid; e < E1_; e += 256)
                partial[((size_t)b * NBLK3_ + mt) * E1_ + e] = 0.f;
        return;
    }
    int w = tid >> 6, lane = tid & 63, lr = lane & 15, lg = lane >> 4;
    int mf = w & 1, nb = (w >> 1) * 4, nc = (w >> 1) ? 3 : 4;
    f32x4 zero = {0.f, 0.f, 0.f, 0.f};
    f32x4 acc[4] = {zero, zero, zero, zero};
    for (int k0 = 0; k0 < 1024; k0 += 64) {
        {   // A: 32 rows x 64 k, split fp32 -> hi/lo on the fly (1 slot per thread)
            int r = tid >> 3, s = tid & 7;
            const float* src = &q_enc[((size_t)b * L_ + l0 + r) * D_ + k0 + s * 8];
            float4 x0 = *(const float4*)src, x1 = *(const float4*)(src + 4);
            float xs[8] = {x0.x, x0.y, x0.z, x0.w, x1.x, x1.y, x1.z, x1.w};
            short8 hv, lv;
            #pragma unroll
            for (int j = 0; j < 8; ++j) {
                u16 hh, ll;
                split2(xs[j], hh, ll);
                hv[j] = (short)hh; lv[j] = (short)ll;
            }
            int dst = r * 64 + ((s ^ (r & 7)) << 3);
            *(float4*)&Ah[dst] = __builtin_bit_cast(float4, hv);
            *(float4*)&Al[dst] = __builtin_bit_cast(float4, lv);
        }
        for (int i = tid; i < 112 * 8; i += 256) {  // B: ep rows (over-read past e=100, finite garbage)
            int r = i >> 3, s = i & 7;
            size_t g = ((size_t)b * E1_ + r) * 1024 + k0 + s * 8;
            int dst = r * 64 + ((s ^ (r & 7)) << 3);
            *(float4*)&Bh[dst] = *(const float4*)&ep_hi[g];
            *(float4*)&Bl[dst] = *(const float4*)&ep_lo[g];
        }
        __syncthreads();
        #pragma unroll
        for (int ks = 0; ks < 64; ks += 32) {
            int sk = (ks >> 3) + lg;
            int rA = mf * 16 + lr;
            int adA = rA * 64 + ((sk ^ (rA & 7)) << 3);
            short8 ah = __builtin_bit_cast(short8, *(const float4*)&Ah[adA]);
            short8 al = __builtin_bit_cast(short8, *(const float4*)&Al[adA]);
            #pragma unroll
            for (int nf = 0; nf < 4; ++nf) {
                if (nf < nc) {
                    int rB = (nb + nf) * 16 + lr;
                    int adB = rB * 64 + ((sk ^ (rB & 7)) << 3);
                    short8 bh = __builtin_bit_cast(short8, *(const float4*)&Bh[adB]);
                    short8 bl = __builtin_bit_cast(short8, *(const float4*)&Bl[adB]);
                    acc[nf] = MFMA16(ah, bh, acc[nf]);
                    acc[nf] = MFMA16(ah, bl, acc[nf]);
                    acc[nf] = MFMA16(al, bh, acc[nf]);
                }
            }
        }
        __syncthreads();
    }
    // dump score frags to LDS: row = mf*16 + lg*4 + reg, col = (nb+nf)*16 + lr
    #pragma unroll
    for (int nf = 0; nf < 4; ++nf)
        if (nf < nc) {
            #pragma unroll
            for (int reg = 0; reg < 4; ++reg)
                Ss[(mf * 16 + lg * 4 + reg) * 113 + (nb + nf) * 16 + lr] = acc[nf][reg];
        }
    __syncthreads();
    // ---- softmax over 101 entities per row
    int l = tid & 31, eg = tid >> 5;
    float h = hint[(size_t)b * L_ + l0 + l];
    float sc[13];
    #pragma unroll
    for (int j = 0; j < 13; ++j) {
        int e = eg + 8 * j;
        sc[j] = (e < E1_) ? (Ss[l * 113 + e] + h * ep_last[b * E1_ + e]) : -3.4e38f;
    }
    float mloc = -3.4e38f;
    #pragma unroll
    for (int j = 0; j < 13; ++j) mloc = fmaxf(mloc, sc[j]);
    red[l][eg] = mloc;
    __syncthreads();
    float m = red[l][0];
    #pragma unroll
    for (int k = 1; k < 8; ++k) m = fmaxf(m, red[l][k]);
    __syncthreads();
    float p[13];
    float sloc = 0.f;
    #pragma unroll
    for (int j = 0; j < 13; ++j) {
        p[j] = 0.f;
        if (eg + 8 * j < E1_) { p[j] = __expf(sc[j] - m); sloc += p[j]; }
    }
    red[l][eg] = sloc;
    __syncthreads();
    float ssum = 0.f;
    #pragma unroll
    for (int k = 0; k < 8; ++k) ssum += red[l][k];
    float inv = 1.f / ssum;
    bool valid = (l0 + l) < qn;
    float maskv = valid ? inv : 0.f;
    // write all rows: valid -> softmax, masked -> 0 (replaces the memset)
    float* row = &co_att[((size_t)b * L_ + l0 + l) * E1_];
    #pragma unroll
    for (int j = 0; j < 13; ++j) {
        int e = eg + 8 * j;
        if (e < E1_) row[e] = p[j] * maskv;
    }
    #pragma unroll
    for (int j = 0; j < 13; ++j) {
        int e = eg + 8 * j;
        float v = (e < E1_) ? p[j] * maskv : 0.f;
        v += __shfl_xor(v, 1);  v += __shfl_xor(v, 2);
        v += __shfl_xor(v, 4);  v += __shfl_xor(v, 8);
        v += __shfl_xor(v, 16);
        if ((tid & 31) == 0 && e < E1_)
            partial[((size_t)b * NBLK3_ + mt) * E1_ + e] = v;
    }
}

// ---------------- K5: att[b,e] = min(sum of partials, 1)
__global__ __launch_bounds__(256) void k_final(const float* __restrict__ partial,
                                               float* __restrict__ att) {
    int i = blockIdx.x * 256 + threadIdx.x;
    if (i >= B_ * E_) return;
    int b = i / E_, e = i % E_;
    float s = 0.f;
    #pragma unroll
    for (int k = 0; k < NBLK3_; ++k) s += partial[((size_t)b * NBLK3_ + k) * E1_ + e];
    att[i] = fminf(s, 1.f);
}

extern "C" void kernel_launch(void* const* d_in, const int* in_sizes, int n_in,
                              void* d_out, int out_size, void* d_ws, size_t ws_size,
                              hipStream_t stream) {
    const float* q_enc    = (const float*)d_in[0];
    const float* hint     = (const float*)d_in[1];
    const float* W        = (const float*)d_in[2];
    const float* bias     = (const float*)d_in[3];
    const float* none_ent = (const float*)d_in[4];
    const int*   qlen     = (const int*)d_in[5];
    const int*   ranges   = (const int*)d_in[6];

    float* att    = (float*)d_out;
    float* co_att = att + (size_t)B_ * E_;

    u16* enc_hi = (u16*)d_ws;
    u16* enc_lo = enc_hi + (size_t)M2P_ * 1024;
    u16* w_hi   = enc_lo + (size_t)M2P_ * 1024;
    u16* w_lo   = w_hi + (size_t)1024 * 1024;
    u16* ep_hi  = w_lo + (size_t)1024 * 1024;
    u16* ep_lo  = ep_hi + (size_t)M2P_ * 1024;
    float* ep_last = (float*)(ep_lo + (size_t)M2P_ * 1024);
    float* part    = ep_last + M2P_;

    k_encode<<<M2_, 256, 0, stream>>>(q_enc, none_ent, W, bias, ranges, enc_hi, enc_lo, ep_last);
    k_wsplit<<<1024, 256, 0, stream>>>(W, w_hi, w_lo);
    k_entproj<<<dim3(16, 51), 256, 0, stream>>>(enc_hi, enc_lo, w_hi, w_lo, bias, ep_hi, ep_lo);
    k_scores<<<dim3(L_ / QBLK_, B_), 256, 0, stream>>>(q_enc, hint, ep_hi, ep_lo, ep_last, qlen, co_att, part);
    k_final<<<13, 256, 0, stream>>>(part, att);
}

// Round 4
// 106.904 us; speedup vs baseline: 1.3360x; 1.3360x over previous
//
#include <hip/hip_runtime.h>
#include <hip/hip_bf16.h>

typedef unsigned short u16;
typedef __attribute__((ext_vector_type(8))) short short8;
typedef __attribute__((ext_vector_type(4))) float f32x4;

#define B_ 32
#define L_ 1024
#define D_ 1024
#define E_ 100
#define E1_ 101
#define M2_ (B_ * E1_)     // 3232 entity rows (incl. none-entity)
#define M2P_ 3264          // padded to 51*64 for MFMA tiles
#define QBLK_ 32
#define NBLK3_ 7           // tiles that can contain valid rows (Q_MAX=200 < 7*32)

#define MFMA16(a, b, c) __builtin_amdgcn_mfma_f32_16x16x32_bf16((a), (b), (c), 0, 0, 0)

__device__ __forceinline__ void split2(float x, u16& h, u16& l) {
    __hip_bfloat16 bh = __float2bfloat16(x);          // RN
    float r = x - __bfloat162float(bh);
    __hip_bfloat16 bl = __float2bfloat16(r);
    h = __builtin_bit_cast(u16, bh);
    l = __builtin_bit_cast(u16, bl);
}

// ---------------- K0: zero co_att rows for tiles >= NBLK3_ (l in [224, 1024))
__global__ __launch_bounds__(256) void k_zerofill(float* __restrict__ co_att) {
    int b = blockIdx.y;
    float4* base = (float4*)&co_att[((size_t)b * L_ + NBLK3_ * QBLK_) * E1_];
    const int n4 = (L_ - NBLK3_ * QBLK_) * E1_ / 4;  // 800*101/4 = 20200
    float4 z = make_float4(0.f, 0.f, 0.f, 0.f);
    for (int i = blockIdx.x * 256 + threadIdx.x; i < n4; i += gridDim.x * 256)
        base[i] = z;
}

// ---------------- K1: segment-sum -> enc hi/lo bf16 split; fused last column
// ep_last[be] = dot(enc_row, W[1024,:]) + bias[1024]
__global__ __launch_bounds__(256) void k_encode(const float* __restrict__ q_enc,
                                                const float* __restrict__ none_ent,
                                                const float* __restrict__ W,
                                                const float* __restrict__ bias,
                                                const int* __restrict__ ranges,
                                                u16* __restrict__ enc_hi, u16* __restrict__ enc_lo,
                                                float* __restrict__ ep_last) {
    __shared__ float red4[4];
    int be = blockIdx.x;
    int b = be / E1_, e = be - b * E1_;
    int t = threadIdx.x, c = t * 4;
    float4 acc;
    if (e == E_) {
        acc = *(const float4*)&none_ent[c];
    } else {
        acc = make_float4(0.f, 0.f, 0.f, 0.f);
        int r0 = ranges[(b * E_ + e) * 2 + 0];
        int r1 = ranges[(b * E_ + e) * 2 + 1];
        for (int l = r0 + 1; l < r1; ++l) {
            float4 v = *(const float4*)&q_enc[((size_t)b * L_ + l) * D_ + c];
            acc.x += v.x; acc.y += v.y; acc.z += v.z; acc.w += v.w;
        }
    }
    union { u16 u[4]; float2 f; } ph, pl;
    split2(acc.x, ph.u[0], pl.u[0]); split2(acc.y, ph.u[1], pl.u[1]);
    split2(acc.z, ph.u[2], pl.u[2]); split2(acc.w, ph.u[3], pl.u[3]);
    *(float2*)&enc_hi[(size_t)be * 1024 + c] = ph.f;
    *(float2*)&enc_lo[(size_t)be * 1024 + c] = pl.f;
    // fused last column (hint-weight row of W)
    const float* w1k = W + (size_t)1024 * 1024;
    float4 wv = *(const float4*)&w1k[c];
    float s = acc.x * wv.x + acc.y * wv.y + acc.z * wv.z + acc.w * wv.w;
    #pragma unroll
    for (int off = 32; off; off >>= 1) s += __shfl_down(s, off);
    if ((t & 63) == 0) red4[t >> 6] = s;
    __syncthreads();
    if (t == 0) ep_last[be] = red4[0] + red4[1] + red4[2] + red4[3] + bias[1024];
}

// ---------------- K2: W rows 0..1023 -> bf16 hi/lo
__global__ __launch_bounds__(256) void k_wsplit(const float* __restrict__ W,
                                                u16* __restrict__ w_hi, u16* __restrict__ w_lo) {
    int r = blockIdx.x, c = threadIdx.x * 4;
    float4 v = *(const float4*)&W[(size_t)r * 1024 + c];
    union { u16 u[4]; float2 f; } ph, pl;
    split2(v.x, ph.u[0], pl.u[0]); split2(v.y, ph.u[1], pl.u[1]);
    split2(v.z, ph.u[2], pl.u[2]); split2(v.w, ph.u[3], pl.u[3]);
    *(float2*)&w_hi[(size_t)r * 1024 + c] = ph.f;
    *(float2*)&w_lo[(size_t)r * 1024 + c] = pl.f;
}

// ---------------- K3: ep[m][n] = enc[m][:] . W[n][:] + bias[n], 3-term bf16 MFMA
// 64x64 tile, BK=64, 4 waves (2x2), wave = 32x32 = 2x2 frags of 16x16x32.
__global__ __launch_bounds__(256) void k_entproj(const u16* __restrict__ A_hi, const u16* __restrict__ A_lo,
                                                 const u16* __restrict__ B_hi, const u16* __restrict__ B_lo,
                                                 const float* __restrict__ bias,
                                                 u16* __restrict__ ep_hi, u16* __restrict__ ep_lo) {
    __shared__ __attribute__((aligned(16))) u16 Ah[64 * 64], Al[64 * 64], Bh[64 * 64], Bl[64 * 64];
    int tid = threadIdx.x;
    int m0 = blockIdx.y * 64, n0 = blockIdx.x * 64;
    int w = tid >> 6, lane = tid & 63, lr = lane & 15, lg = lane >> 4;
    int wr = w >> 1, wc = w & 1;
    f32x4 zero = {0.f, 0.f, 0.f, 0.f};
    f32x4 acc[2][2] = {{zero, zero}, {zero, zero}};
    for (int k0 = 0; k0 < 1024; k0 += 64) {
        #pragma unroll
        for (int p = 0; p < 2; ++p) {
            int i = p * 256 + tid, r = i >> 3, s = i & 7;
            int dst = r * 64 + ((s ^ (r & 7)) << 3);
            size_t ga = (size_t)(m0 + r) * 1024 + k0 + s * 8;
            size_t gb = (size_t)(n0 + r) * 1024 + k0 + s * 8;
            *(float4*)&Ah[dst] = *(const float4*)&A_hi[ga];
            *(float4*)&Al[dst] = *(const float4*)&A_lo[ga];
            *(float4*)&Bh[dst] = *(const float4*)&B_hi[gb];
            *(float4*)&Bl[dst] = *(const float4*)&B_lo[gb];
        }
        __syncthreads();
        #pragma unroll
        for (int ks = 0; ks < 64; ks += 32) {
            int sk = (ks >> 3) + lg;
            short8 ah[2], al[2], bh[2], bl[2];
            #pragma unroll
            for (int mf = 0; mf < 2; ++mf) {
                int r = wr * 32 + mf * 16 + lr;
                int ad = r * 64 + ((sk ^ (r & 7)) << 3);
                ah[mf] = __builtin_bit_cast(short8, *(const float4*)&Ah[ad]);
                al[mf] = __builtin_bit_cast(short8, *(const float4*)&Al[ad]);
            }
            #pragma unroll
            for (int nf = 0; nf < 2; ++nf) {
                int r = wc * 32 + nf * 16 + lr;
                int ad = r * 64 + ((sk ^ (r & 7)) << 3);
                bh[nf] = __builtin_bit_cast(short8, *(const float4*)&Bh[ad]);
                bl[nf] = __builtin_bit_cast(short8, *(const float4*)&Bl[ad]);
            }
            #pragma unroll
            for (int mf = 0; mf < 2; ++mf)
                #pragma unroll
                for (int nf = 0; nf < 2; ++nf) {
                    acc[mf][nf] = MFMA16(ah[mf], bh[nf], acc[mf][nf]);
                    acc[mf][nf] = MFMA16(ah[mf], bl[nf], acc[mf][nf]);
                    acc[mf][nf] = MFMA16(al[mf], bh[nf], acc[mf][nf]);
                }
        }
        __syncthreads();
    }
    #pragma unroll
    for (int mf = 0; mf < 2; ++mf)
        #pragma unroll
        for (int nf = 0; nf < 2; ++nf)
            #pragma unroll
            for (int reg = 0; reg < 4; ++reg) {
                int m = m0 + wr * 32 + mf * 16 + lg * 4 + reg;
                if (m < M2_) {
                    int n = n0 + wc * 32 + nf * 16 + lr;
                    float v = acc[mf][nf][reg] + bias[n];
                    u16 h, l;
                    split2(v, h, l);
                    ep_hi[(size_t)m * 1024 + n] = h;
                    ep_lo[(size_t)m * 1024 + n] = l;
                }
            }
}

// ---------------- K4: scores (MFMA) + fused softmax + co_att writes (incl. masked-row zeros)
// grid = (NBLK3_, B) — spreads 224 heavy blocks ~1/CU (avoid the 32-wide grid XCD stacking).
__global__ __launch_bounds__(256) void k_scores(const float* __restrict__ q_enc,
                                                const float* __restrict__ hint,
                                                const u16* __restrict__ ep_hi, const u16* __restrict__ ep_lo,
                                                const float* __restrict__ ep_last,
                                                const int* __restrict__ qlen,
                                                float* __restrict__ co_att,
                                                float* __restrict__ partial) {
    __shared__ __attribute__((aligned(16))) u16 Ah[32 * 64], Al[32 * 64], Bh[112 * 64], Bl[112 * 64];
    __shared__ float Ss[32 * 113];
    __shared__ float red[QBLK_][8];
    int b = blockIdx.y, mt = blockIdx.x, l0 = mt * QBLK_;
    int tid = threadIdx.x;
    int qn = qlen[b];
    if (l0 >= qn) {
        // zero this tile's co_att rows (32*101 floats = 808 float4, 16B-aligned)
        float* base = &co_att[((size_t)b * L_ + l0) * E1_];
        float4 z = make_float4(0.f, 0.f, 0.f, 0.f);
        for (int i = tid; i < QBLK_ * E1_ / 4; i += 256)
            *(float4*)&base[i * 4] = z;
        for (int e = tid; e < E1_; e += 256)
            partial[((size_t)b * NBLK3_ + mt) * E1_ + e] = 0.f;
        return;
    }
    int w = tid >> 6, lane = tid & 63, lr = lane & 15, lg = lane >> 4;
    int mf = w & 1, nb = (w >> 1) * 4, nc = (w >> 1) ? 3 : 4;
    f32x4 zero = {0.f, 0.f, 0.f, 0.f};
    f32x4 acc[4] = {zero, zero, zero, zero};
    for (int k0 = 0; k0 < 1024; k0 += 64) {
        {   // A: 32 rows x 64 k, split fp32 -> hi/lo on the fly (1 slot per thread)
            int r = tid >> 3, s = tid & 7;
            const float* src = &q_enc[((size_t)b * L_ + l0 + r) * D_ + k0 + s * 8];
            float4 x0 = *(const float4*)src, x1 = *(const float4*)(src + 4);
            float xs[8] = {x0.x, x0.y, x0.z, x0.w, x1.x, x1.y, x1.z, x1.w};
            short8 hv, lv;
            #pragma unroll
            for (int j = 0; j < 8; ++j) {
                u16 hh, ll;
                split2(xs[j], hh, ll);
                hv[j] = (short)hh; lv[j] = (short)ll;
            }
            int dst = r * 64 + ((s ^ (r & 7)) << 3);
            *(float4*)&Ah[dst] = __builtin_bit_cast(float4, hv);
            *(float4*)&Al[dst] = __builtin_bit_cast(float4, lv);
        }
        for (int i = tid; i < 112 * 8; i += 256) {  // B: ep rows (over-read past e=100, finite garbage)
            int r = i >> 3, s = i & 7;
            size_t g = ((size_t)b * E1_ + r) * 1024 + k0 + s * 8;
            int dst = r * 64 + ((s ^ (r & 7)) << 3);
            *(float4*)&Bh[dst] = *(const float4*)&ep_hi[g];
            *(float4*)&Bl[dst] = *(const float4*)&ep_lo[g];
        }
        __syncthreads();
        #pragma unroll
        for (int ks = 0; ks < 64; ks += 32) {
            int sk = (ks >> 3) + lg;
            int rA = mf * 16 + lr;
            int adA = rA * 64 + ((sk ^ (rA & 7)) << 3);
            short8 ah = __builtin_bit_cast(short8, *(const float4*)&Ah[adA]);
            short8 al = __builtin_bit_cast(short8, *(const float4*)&Al[adA]);
            #pragma unroll
            for (int nf = 0; nf < 4; ++nf) {
                if (nf < nc) {
                    int rB = (nb + nf) * 16 + lr;
                    int adB = rB * 64 + ((sk ^ (rB & 7)) << 3);
                    short8 bh = __builtin_bit_cast(short8, *(const float4*)&Bh[adB]);
                    short8 bl = __builtin_bit_cast(short8, *(const float4*)&Bl[adB]);
                    acc[nf] = MFMA16(ah, bh, acc[nf]);
                    acc[nf] = MFMA16(ah, bl, acc[nf]);
                    acc[nf] = MFMA16(al, bh, acc[nf]);
                }
            }
        }
        __syncthreads();
    }
    // dump score frags to LDS: row = mf*16 + lg*4 + reg, col = (nb+nf)*16 + lr
    #pragma unroll
    for (int nf = 0; nf < 4; ++nf)
        if (nf < nc) {
            #pragma unroll
            for (int reg = 0; reg < 4; ++reg)
                Ss[(mf * 16 + lg * 4 + reg) * 113 + (nb + nf) * 16 + lr] = acc[nf][reg];
        }
    __syncthreads();
    // ---- softmax over 101 entities per row
    int l = tid & 31, eg = tid >> 5;
    float h = hint[(size_t)b * L_ + l0 + l];
    float sc[13];
    #pragma unroll
    for (int j = 0; j < 13; ++j) {
        int e = eg + 8 * j;
        sc[j] = (e < E1_) ? (Ss[l * 113 + e] + h * ep_last[b * E1_ + e]) : -3.4e38f;
    }
    float mloc = -3.4e38f;
    #pragma unroll
    for (int j = 0; j < 13; ++j) mloc = fmaxf(mloc, sc[j]);
    red[l][eg] = mloc;
    __syncthreads();
    float m = red[l][0];
    #pragma unroll
    for (int k = 1; k < 8; ++k) m = fmaxf(m, red[l][k]);
    __syncthreads();
    float p[13];
    float sloc = 0.f;
    #pragma unroll
    for (int j = 0; j < 13; ++j) {
        p[j] = 0.f;
        if (eg + 8 * j < E1_) { p[j] = __expf(sc[j] - m); sloc += p[j]; }
    }
    red[l][eg] = sloc;
    __syncthreads();
    float ssum = 0.f;
    #pragma unroll
    for (int k = 0; k < 8; ++k) ssum += red[l][k];
    float inv = 1.f / ssum;
    bool valid = (l0 + l) < qn;
    float maskv = valid ? inv : 0.f;
    // write all rows of this tile: valid -> softmax, masked -> 0
    float* row = &co_att[((size_t)b * L_ + l0 + l) * E1_];
    #pragma unroll
    for (int j = 0; j < 13; ++j) {
        int e = eg + 8 * j;
        if (e < E1_) row[e] = p[j] * maskv;
    }
    #pragma unroll
    for (int j = 0; j < 13; ++j) {
        int e = eg + 8 * j;
        float v = (e < E1_) ? p[j] * maskv : 0.f;
        v += __shfl_xor(v, 1);  v += __shfl_xor(v, 2);
        v += __shfl_xor(v, 4);  v += __shfl_xor(v, 8);
        v += __shfl_xor(v, 16);
        if ((tid & 31) == 0 && e < E1_)
            partial[((size_t)b * NBLK3_ + mt) * E1_ + e] = v;
    }
}

// ---------------- K5: att[b,e] = min(sum of partials, 1)
__global__ __launch_bounds__(256) void k_final(const float* __restrict__ partial,
                                               float* __restrict__ att) {
    int i = blockIdx.x * 256 + threadIdx.x;
    if (i >= B_ * E_) return;
    int b = i / E_, e = i % E_;
    float s = 0.f;
    #pragma unroll
    for (int k = 0; k < NBLK3_; ++k) s += partial[((size_t)b * NBLK3_ + k) * E1_ + e];
    att[i] = fminf(s, 1.f);
}

extern "C" void kernel_launch(void* const* d_in, const int* in_sizes, int n_in,
                              void* d_out, int out_size, void* d_ws, size_t ws_size,
                              hipStream_t stream) {
    const float* q_enc    = (const float*)d_in[0];
    const float* hint     = (const float*)d_in[1];
    const float* W        = (const float*)d_in[2];
    const float* bias     = (const float*)d_in[3];
    const float* none_ent = (const float*)d_in[4];
    const int*   qlen     = (const int*)d_in[5];
    const int*   ranges   = (const int*)d_in[6];

    float* att    = (float*)d_out;
    float* co_att = att + (size_t)B_ * E_;

    u16* enc_hi = (u16*)d_ws;
    u16* enc_lo = enc_hi + (size_t)M2P_ * 1024;
    u16* w_hi   = enc_lo + (size_t)M2P_ * 1024;
    u16* w_lo   = w_hi + (size_t)1024 * 1024;
    u16* ep_hi  = w_lo + (size_t)1024 * 1024;
    u16* ep_lo  = ep_hi + (size_t)M2P_ * 1024;
    float* ep_last = (float*)(ep_lo + (size_t)M2P_ * 1024);
    float* part    = ep_last + M2P_;

    k_zerofill<<<dim3(20, B_), 256, 0, stream>>>(co_att);
    k_encode<<<M2_, 256, 0, stream>>>(q_enc, none_ent, W, bias, ranges, enc_hi, enc_lo, ep_last);
    k_wsplit<<<1024, 256, 0, stream>>>(W, w_hi, w_lo);
    k_entproj<<<dim3(16, 51), 256, 0, stream>>>(enc_hi, enc_lo, w_hi, w_lo, bias, ep_hi, ep_lo);
    k_scores<<<dim3(NBLK3_, B_), 256, 0, stream>>>(q_enc, hint, ep_hi, ep_lo, ep_last, qlen, co_att, part);
    k_final<<<13, 256, 0, stream>>>(part, att);
}

// Round 5
// 101.656 us; speedup vs baseline: 1.4050x; 1.0516x over previous
//
#include <hip/hip_runtime.h>
#include <hip/hip_bf16.h>

typedef unsigned short u16;
typedef __attribute__((ext_vector_type(8))) short short8;
typedef __attribute__((ext_vector_type(4))) float f32x4;

#define B_ 32
#define L_ 1024
#define D_ 1024
#define E_ 100
#define E1_ 101
#define M2_ (B_ * E1_)     // 3232 entity rows (incl. none-entity)
#define M2P_ 3328          // padded to 26*128 for the 128-row MFMA tiles
#define QBLK_ 32
#define NBLK3_ 7           // tiles that can contain valid rows (Q_MAX=200 < 7*32)

#define MFMA16(a, b, c) __builtin_amdgcn_mfma_f32_16x16x32_bf16((a), (b), (c), 0, 0, 0)

__device__ __forceinline__ void split2(float x, u16& h, u16& l) {
    __hip_bfloat16 bh = __float2bfloat16(x);          // RN
    float r = x - __bfloat162float(bh);
    __hip_bfloat16 bl = __float2bfloat16(r);
    h = __builtin_bit_cast(u16, bh);
    l = __builtin_bit_cast(u16, bl);
}

// async global->LDS, 16B per lane; LDS dest = wave-uniform base + lane*16
__device__ __forceinline__ void gload16(const void* g, void* l) {
    __builtin_amdgcn_global_load_lds(
        (const __attribute__((address_space(1))) unsigned int*)g,
        (__attribute__((address_space(3))) unsigned int*)l, 16, 0, 0);
}

// ---------------- K0: zero co_att rows for tiles >= NBLK3_ (l in [224, 1024))
__global__ __launch_bounds__(256) void k_zerofill(float* __restrict__ co_att) {
    int b = blockIdx.y;
    float4* base = (float4*)&co_att[((size_t)b * L_ + NBLK3_ * QBLK_) * E1_];
    const int n4 = (L_ - NBLK3_ * QBLK_) * E1_ / 4;  // 800*101/4 = 20200
    float4 z = make_float4(0.f, 0.f, 0.f, 0.f);
    for (int i = blockIdx.x * 256 + threadIdx.x; i < n4; i += gridDim.x * 256)
        base[i] = z;
}

// ---------------- K1: segment-sum -> enc hi/lo bf16 split; fused last column
__global__ __launch_bounds__(256) void k_encode(const float* __restrict__ q_enc,
                                                const float* __restrict__ none_ent,
                                                const float* __restrict__ W,
                                                const float* __restrict__ bias,
                                                const int* __restrict__ ranges,
                                                u16* __restrict__ enc_hi, u16* __restrict__ enc_lo,
                                                float* __restrict__ ep_last) {
    __shared__ float red4[4];
    int be = blockIdx.x;
    int b = be / E1_, e = be - b * E1_;
    int t = threadIdx.x, c = t * 4;
    float4 acc;
    if (e == E_) {
        acc = *(const float4*)&none_ent[c];
    } else {
        acc = make_float4(0.f, 0.f, 0.f, 0.f);
        int r0 = ranges[(b * E_ + e) * 2 + 0];
        int r1 = ranges[(b * E_ + e) * 2 + 1];
        for (int l = r0 + 1; l < r1; ++l) {
            float4 v = *(const float4*)&q_enc[((size_t)b * L_ + l) * D_ + c];
            acc.x += v.x; acc.y += v.y; acc.z += v.z; acc.w += v.w;
        }
    }
    union { u16 u[4]; float2 f; } ph, pl;
    split2(acc.x, ph.u[0], pl.u[0]); split2(acc.y, ph.u[1], pl.u[1]);
    split2(acc.z, ph.u[2], pl.u[2]); split2(acc.w, ph.u[3], pl.u[3]);
    *(float2*)&enc_hi[(size_t)be * 1024 + c] = ph.f;
    *(float2*)&enc_lo[(size_t)be * 1024 + c] = pl.f;
    const float* w1k = W + (size_t)1024 * 1024;
    float4 wv = *(const float4*)&w1k[c];
    float s = acc.x * wv.x + acc.y * wv.y + acc.z * wv.z + acc.w * wv.w;
    #pragma unroll
    for (int off = 32; off; off >>= 1) s += __shfl_down(s, off);
    if ((t & 63) == 0) red4[t >> 6] = s;
    __syncthreads();
    if (t == 0) ep_last[be] = red4[0] + red4[1] + red4[2] + red4[3] + bias[1024];
}

// ---------------- K2: W rows 0..1023 -> bf16 hi/lo
__global__ __launch_bounds__(256) void k_wsplit(const float* __restrict__ W,
                                                u16* __restrict__ w_hi, u16* __restrict__ w_lo) {
    int r = blockIdx.x, c = threadIdx.x * 4;
    float4 v = *(const float4*)&W[(size_t)r * 1024 + c];
    union { u16 u[4]; float2 f; } ph, pl;
    split2(v.x, ph.u[0], pl.u[0]); split2(v.y, ph.u[1], pl.u[1]);
    split2(v.z, ph.u[2], pl.u[2]); split2(v.w, ph.u[3], pl.u[3]);
    *(float2*)&w_hi[(size_t)r * 1024 + c] = ph.f;
    *(float2*)&w_lo[(size_t)r * 1024 + c] = pl.f;
}

// ---------------- K3: ep = enc . W^T + bias, 3-term bf16 MFMA
// 128x128 tile, BK=64, global_load_lds staging (pre-swizzled global source,
// linear LDS dest). 4 waves (2x2), each 64x64 out = 4x4 frags of 16x16x32.
__global__ __launch_bounds__(256, 2) void k_entproj(const u16* __restrict__ A_hi, const u16* __restrict__ A_lo,
                                                    const u16* __restrict__ B_hi, const u16* __restrict__ B_lo,
                                                    const float* __restrict__ bias,
                                                    u16* __restrict__ ep_hi, u16* __restrict__ ep_lo) {
    __shared__ __attribute__((aligned(16))) u16 Ah[128 * 64], Al[128 * 64], Bh[128 * 64], Bl[128 * 64];
    int tid = threadIdx.x;
    int m0 = blockIdx.y * 128, n0 = blockIdx.x * 128;
    int w = tid >> 6, lane = tid & 63, lr = lane & 15, lg = lane >> 4;
    int wr = w >> 1, wc = w & 1;
    f32x4 zero = {0.f, 0.f, 0.f, 0.f};
    f32x4 acc[4][4];
    #pragma unroll
    for (int i = 0; i < 4; ++i)
        #pragma unroll
        for (int j = 0; j < 4; ++j) acc[i][j] = zero;
    int sb = w * 256;                 // wave's slot base (of 1024 slots/array)
    for (int k0 = 0; k0 < 1024; k0 += 64) {
        #pragma unroll
        for (int j = 0; j < 4; ++j) {
            int slot = sb + j * 64 + lane;      // slot = r*8 + s
            int r = slot >> 3, s = slot & 7;
            int g = (s ^ (r & 7)) << 3;         // pre-swizzled source column group
            size_t ga = (size_t)(m0 + r) * 1024 + k0 + g;
            size_t gb = (size_t)(n0 + r) * 1024 + k0 + g;
            int ld = (sb + j * 64) * 8;         // wave-uniform LDS base (u16 idx)
            gload16(&A_hi[ga], &Ah[ld]);
            gload16(&A_lo[ga], &Al[ld]);
            gload16(&B_hi[gb], &Bh[ld]);
            gload16(&B_lo[gb], &Bl[ld]);
        }
        __syncthreads();
        #pragma unroll
        for (int half = 0; half < 2; ++half) {
            int sk = half * 4 + lg;
            short8 a_h[4], a_l[4], b_h[4], b_l[4];
            #pragma unroll
            for (int mf = 0; mf < 4; ++mf) {
                int R = wr * 64 + mf * 16 + lr;
                int ad = R * 64 + ((sk ^ (R & 7)) << 3);
                a_h[mf] = __builtin_bit_cast(short8, *(const float4*)&Ah[ad]);
                a_l[mf] = __builtin_bit_cast(short8, *(const float4*)&Al[ad]);
            }
            #pragma unroll
            for (int nf = 0; nf < 4; ++nf) {
                int R = wc * 64 + nf * 16 + lr;
                int ad = R * 64 + ((sk ^ (R & 7)) << 3);
                b_h[nf] = __builtin_bit_cast(short8, *(const float4*)&Bh[ad]);
                b_l[nf] = __builtin_bit_cast(short8, *(const float4*)&Bl[ad]);
            }
            #pragma unroll
            for (int mf = 0; mf < 4; ++mf)
                #pragma unroll
                for (int nf = 0; nf < 4; ++nf) {
                    acc[mf][nf] = MFMA16(a_h[mf], b_h[nf], acc[mf][nf]);
                    acc[mf][nf] = MFMA16(a_h[mf], b_l[nf], acc[mf][nf]);
                    acc[mf][nf] = MFMA16(a_l[mf], b_h[nf], acc[mf][nf]);
                }
        }
        __syncthreads();
    }
    #pragma unroll
    for (int mf = 0; mf < 4; ++mf)
        #pragma unroll
        for (int nf = 0; nf < 4; ++nf)
            #pragma unroll
            for (int reg = 0; reg < 4; ++reg) {
                int m = m0 + wr * 64 + mf * 16 + lg * 4 + reg;
                if (m < M2_) {
                    int n = n0 + wc * 64 + nf * 16 + lr;
                    float v = acc[mf][nf][reg] + bias[n];
                    u16 h, l;
                    split2(v, h, l);
                    ep_hi[(size_t)m * 1024 + n] = h;
                    ep_lo[(size_t)m * 1024 + n] = l;
                }
            }
}

// ---------------- K4: scores (MFMA) + fused softmax + co_att writes
// grid = (NBLK3_, B). B-staging via global_load_lds (rows padded to 128).
__global__ __launch_bounds__(256) void k_scores(const float* __restrict__ q_enc,
                                                const float* __restrict__ hint,
                                                const u16* __restrict__ ep_hi, const u16* __restrict__ ep_lo,
                                                const float* __restrict__ ep_last,
                                                const int* __restrict__ qlen,
                                                float* __restrict__ co_att,
                                                float* __restrict__ partial) {
    __shared__ __attribute__((aligned(16))) u16 Ah[32 * 64], Al[32 * 64], Bh[128 * 64], Bl[128 * 64];
    __shared__ float Ss[32 * 113];
    __shared__ float red[QBLK_][8];
    int b = blockIdx.y, mt = blockIdx.x, l0 = mt * QBLK_;
    int tid = threadIdx.x;
    int qn = qlen[b];
    if (l0 >= qn) {
        float* base = &co_att[((size_t)b * L_ + l0) * E1_];
        float4 z = make_float4(0.f, 0.f, 0.f, 0.f);
        for (int i = tid; i < QBLK_ * E1_ / 4; i += 256)
            *(float4*)&base[i * 4] = z;
        for (int e = tid; e < E1_; e += 256)
            partial[((size_t)b * NBLK3_ + mt) * E1_ + e] = 0.f;
        return;
    }
    int w = tid >> 6, lane = tid & 63, lr = lane & 15, lg = lane >> 4;
    int mf = w & 1, nb = (w >> 1) * 4, nc = (w >> 1) ? 3 : 4;
    int sb = w * 256;
    f32x4 zero = {0.f, 0.f, 0.f, 0.f};
    f32x4 acc[4] = {zero, zero, zero, zero};
    for (int k0 = 0; k0 < 1024; k0 += 64) {
        {   // B: 128 rows x 64 k via gload_lds (rows >100 are finite garbage, masked later)
            #pragma unroll
            for (int j = 0; j < 4; ++j) {
                int slot = sb + j * 64 + lane;
                int r = slot >> 3, s = slot & 7;
                int g = (s ^ (r & 7)) << 3;
                size_t gb = ((size_t)b * E1_ + r) * 1024 + k0 + g;
                int ld = (sb + j * 64) * 8;
                gload16(&ep_hi[gb], &Bh[ld]);
                gload16(&ep_lo[gb], &Bl[ld]);
            }
        }
        {   // A: 32 rows x 64 k, split fp32 -> hi/lo on the fly (1 slot per thread)
            int r = tid >> 3, s = tid & 7;
            const float* src = &q_enc[((size_t)b * L_ + l0 + r) * D_ + k0 + s * 8];
            float4 x0 = *(const float4*)src, x1 = *(const float4*)(src + 4);
            float xs[8] = {x0.x, x0.y, x0.z, x0.w, x1.x, x1.y, x1.z, x1.w};
            short8 hv, lv;
            #pragma unroll
            for (int j = 0; j < 8; ++j) {
                u16 hh, ll;
                split2(xs[j], hh, ll);
                hv[j] = (short)hh; lv[j] = (short)ll;
            }
            int dst = r * 64 + ((s ^ (r & 7)) << 3);
            *(float4*)&Ah[dst] = __builtin_bit_cast(float4, hv);
            *(float4*)&Al[dst] = __builtin_bit_cast(float4, lv);
        }
        __syncthreads();
        #pragma unroll
        for (int ks = 0; ks < 64; ks += 32) {
            int sk = (ks >> 3) + lg;
            int rA = mf * 16 + lr;
            int adA = rA * 64 + ((sk ^ (rA & 7)) << 3);
            short8 ah = __builtin_bit_cast(short8, *(const float4*)&Ah[adA]);
            short8 al = __builtin_bit_cast(short8, *(const float4*)&Al[adA]);
            #pragma unroll
            for (int nf = 0; nf < 4; ++nf) {
                if (nf < nc) {
                    int rB = (nb + nf) * 16 + lr;
                    int adB = rB * 64 + ((sk ^ (rB & 7)) << 3);
                    short8 bh = __builtin_bit_cast(short8, *(const float4*)&Bh[adB]);
                    short8 bl = __builtin_bit_cast(short8, *(const float4*)&Bl[adB]);
                    acc[nf] = MFMA16(ah, bh, acc[nf]);
                    acc[nf] = MFMA16(ah, bl, acc[nf]);
                    acc[nf] = MFMA16(al, bh, acc[nf]);
                }
            }
        }
        __syncthreads();
    }
    #pragma unroll
    for (int nf = 0; nf < 4; ++nf)
        if (nf < nc) {
            #pragma unroll
            for (int reg = 0; reg < 4; ++reg)
                Ss[(mf * 16 + lg * 4 + reg) * 113 + (nb + nf) * 16 + lr] = acc[nf][reg];
        }
    __syncthreads();
    // ---- softmax over 101 entities per row
    int l = tid & 31, eg = tid >> 5;
    float h = hint[(size_t)b * L_ + l0 + l];
    float sc[13];
    #pragma unroll
    for (int j = 0; j < 13; ++j) {
        int e = eg + 8 * j;
        sc[j] = (e < E1_) ? (Ss[l * 113 + e] + h * ep_last[b * E1_ + e]) : -3.4e38f;
    }
    float mloc = -3.4e38f;
    #pragma unroll
    for (int j = 0; j < 13; ++j) mloc = fmaxf(mloc, sc[j]);
    red[l][eg] = mloc;
    __syncthreads();
    float m = red[l][0];
    #pragma unroll
    for (int k = 1; k < 8; ++k) m = fmaxf(m, red[l][k]);
    __syncthreads();
    float p[13];
    float sloc = 0.f;
    #pragma unroll
    for (int j = 0; j < 13; ++j) {
        p[j] = 0.f;
        if (eg + 8 * j < E1_) { p[j] = __expf(sc[j] - m); sloc += p[j]; }
    }
    red[l][eg] = sloc;
    __syncthreads();
    float ssum = 0.f;
    #pragma unroll
    for (int k = 0; k < 8; ++k) ssum += red[l][k];
    float inv = 1.f / ssum;
    bool valid = (l0 + l) < qn;
    float maskv = valid ? inv : 0.f;
    float* row = &co_att[((size_t)b * L_ + l0 + l) * E1_];
    #pragma unroll
    for (int j = 0; j < 13; ++j) {
        int e = eg + 8 * j;
        if (e < E1_) row[e] = p[j] * maskv;
    }
    #pragma unroll
    for (int j = 0; j < 13; ++j) {
        int e = eg + 8 * j;
        float v = (e < E1_) ? p[j] * maskv : 0.f;
        v += __shfl_xor(v, 1);  v += __shfl_xor(v, 2);
        v += __shfl_xor(v, 4);  v += __shfl_xor(v, 8);
        v += __shfl_xor(v, 16);
        if ((tid & 31) == 0 && e < E1_)
            partial[((size_t)b * NBLK3_ + mt) * E1_ + e] = v;
    }
}

// ---------------- K5: att[b,e] = min(sum of partials, 1)
__global__ __launch_bounds__(256) void k_final(const float* __restrict__ partial,
                                               float* __restrict__ att) {
    int i = blockIdx.x * 256 + threadIdx.x;
    if (i >= B_ * E_) return;
    int b = i / E_, e = i % E_;
    float s = 0.f;
    #pragma unroll
    for (int k = 0; k < NBLK3_; ++k) s += partial[((size_t)b * NBLK3_ + k) * E1_ + e];
    att[i] = fminf(s, 1.f);
}

extern "C" void kernel_launch(void* const* d_in, const int* in_sizes, int n_in,
                              void* d_out, int out_size, void* d_ws, size_t ws_size,
                              hipStream_t stream) {
    const float* q_enc    = (const float*)d_in[0];
    const float* hint     = (const float*)d_in[1];
    const float* W        = (const float*)d_in[2];
    const float* bias     = (const float*)d_in[3];
    const float* none_ent = (const float*)d_in[4];
    const int*   qlen     = (const int*)d_in[5];
    const int*   ranges   = (const int*)d_in[6];

    float* att    = (float*)d_out;
    float* co_att = att + (size_t)B_ * E_;

    u16* enc_hi = (u16*)d_ws;
    u16* enc_lo = enc_hi + (size_t)M2P_ * 1024;
    u16* w_hi   = enc_lo + (size_t)M2P_ * 1024;
    u16* w_lo   = w_hi + (size_t)1024 * 1024;
    u16* ep_hi  = w_lo + (size_t)1024 * 1024;
    u16* ep_lo  = ep_hi + (size_t)M2P_ * 1024;
    float* ep_last = (float*)(ep_lo + (size_t)M2P_ * 1024);
    float* part    = ep_last + M2P_;

    k_zerofill<<<dim3(20, B_), 256, 0, stream>>>(co_att);
    k_encode<<<M2_, 256, 0, stream>>>(q_enc, none_ent, W, bias, ranges, enc_hi, enc_lo, ep_last);
    k_wsplit<<<1024, 256, 0, stream>>>(W, w_hi, w_lo);
    k_entproj<<<dim3(8, 26), 256, 0, stream>>>(enc_hi, enc_lo, w_hi, w_lo, bias, ep_hi, ep_lo);
    k_scores<<<dim3(NBLK3_, B_), 256, 0, stream>>>(q_enc, hint, ep_hi, ep_lo, ep_last, qlen, co_att, part);
    k_final<<<13, 256, 0, stream>>>(part, att);
}